// Round 4
// baseline (22750.166 us; speedup 1.0000x reference)
//
#include <hip/hip_runtime.h>
#include <math.h>

#define TSTEPS 16384
#define NTAGS  1024
#define NWG    256
#define TPB    64
#define START_I 1022
#define STOP_I  1023

// CRF forward, linear (exp) domain, f32 ring (round-2-proven numerics) +
// latency-tuned structure: 1 wave/CU, 4 rows/wave, 64B/lane sc1 polls,
// DPP row_shr + shfl_xor reductions, 16B/step store per wave.
//   p_{t+1} = e_t . (M p_t) / max(p_t),  S += log(max(p_t))
//   alpha   = S + log( sum_i p_T[i] * exp(trans[STOP,i]) )
// Ring values: sign(t)*(p+1), sign flips every ring wrap (depth-2 ring);
// 0xAA poison (-3e-13) and stale opposite-sign values never validate.

typedef float f32x4 __attribute__((ext_vector_type(4)));

template <int CTRL>
static __device__ __forceinline__ float dppf(float x) {
    return __int_as_float(__builtin_amdgcn_update_dpp(
        0, __float_as_int(x), CTRL, 0xF, 0xF, true));
}
// wave64 sum -> lane 63: DPP row_shr prefix within 16-lane rows, then two
// shfl_xor folds across rows (no row_bcast — hedged semantics).
static __device__ __forceinline__ float red_sum64(float x) {
    x += dppf<0x111>(x);
    x += dppf<0x112>(x);
    x += dppf<0x114>(x);
    x += dppf<0x118>(x);            // lane 15 of each row = row sum
    x += __shfl_xor(x, 16, 64);
    x += __shfl_xor(x, 32, 64);
    return x;                       // lane 63 = full sum
}
static __device__ __forceinline__ float red_max64(float x) {   // x >= 0
    x = fmaxf(x, dppf<0x111>(x));
    x = fmaxf(x, dppf<0x112>(x));
    x = fmaxf(x, dppf<0x114>(x));
    x = fmaxf(x, dppf<0x118>(x));
    x = fmaxf(x, __shfl_xor(x, 16, 64));
    x = fmaxf(x, __shfl_xor(x, 32, 64));
    return x;                       // lane 63 = max
}

// 64B agent-coherent load: 4x dwordx4 from one base, single waitcnt
static __device__ __forceinline__ void llc_load64B(const float* p,
        f32x4& A, f32x4& B, f32x4& C, f32x4& D) {
    unsigned long long ap = (unsigned long long)p;
    asm volatile(
        "global_load_dwordx4 %0, %4, off sc1\n\t"
        "global_load_dwordx4 %1, %4, off offset:16 sc1\n\t"
        "global_load_dwordx4 %2, %4, off offset:32 sc1\n\t"
        "global_load_dwordx4 %3, %4, off offset:48 sc1\n\t"
        "s_waitcnt vmcnt(0)"
        : "=&v"(A), "=&v"(B), "=&v"(C), "=&v"(D)
        : "v"(ap) : "memory");
}

static __device__ __forceinline__ f32x4 vmin4(f32x4 a, f32x4 b) {
    f32x4 r; r.x=fminf(a.x,b.x); r.y=fminf(a.y,b.y);
    r.z=fminf(a.z,b.z); r.w=fminf(a.w,b.w); return r;
}
static __device__ __forceinline__ f32x4 vmax4(f32x4 a, f32x4 b) {
    f32x4 r; r.x=fmaxf(a.x,b.x); r.y=fmaxf(a.y,b.y);
    r.z=fmaxf(a.z,b.z); r.w=fmaxf(a.w,b.w); return r;
}
static __device__ __forceinline__ float hmin16(f32x4 A,f32x4 B,f32x4 C,f32x4 D){
    f32x4 m = vmin4(vmin4(A,B), vmin4(C,D));
    return fminf(fminf(m.x,m.y), fminf(m.z,m.w));
}
static __device__ __forceinline__ float hmax16(f32x4 A,f32x4 B,f32x4 C,f32x4 D){
    f32x4 m = vmax4(vmax4(A,B), vmax4(C,D));
    return fmaxf(fmaxf(m.x,m.y), fmaxf(m.z,m.w));
}
static __device__ __forceinline__ unsigned long long pk2(float a, float b) {
    return (unsigned long long)__float_as_uint(a)
         | ((unsigned long long)__float_as_uint(b) << 32);
}

__global__ __launch_bounds__(TPB)
void crf_forward_kernel(const float* __restrict__ decoded,
                        const float* __restrict__ trans,
                        float* __restrict__ out,
                        float* __restrict__ ring)
{
    const int lane = threadIdx.x;     // 0..63
    const int wg   = blockIdx.x;      // 0..255
    const int r0   = wg * 4;          // this wave's 4 output tags
    const int c0   = 16 * lane;       // this lane's 16 contiguous columns

    // M fragments (f32) + full-row sums (lane 63)
    float M0[16], M1[16], M2[16], M3[16];
    #pragma unroll
    for (int j = 0; j < 16; ++j) {
        M0[j] = __expf(trans[(size_t)(r0+0) * NTAGS + c0 + j]);
        M1[j] = __expf(trans[(size_t)(r0+1) * NTAGS + c0 + j]);
        M2[j] = __expf(trans[(size_t)(r0+2) * NTAGS + c0 + j]);
        M3[j] = __expf(trans[(size_t)(r0+3) * NTAGS + c0 + j]);
    }
    float ms0=0.f, ms1=0.f, ms2=0.f, ms3=0.f;
    #pragma unroll
    for (int j = 0; j < 16; ++j) { ms0+=M0[j]; ms1+=M1[j]; ms2+=M2[j]; ms3+=M3[j]; }
    ms0 = red_sum64(ms0); ms1 = red_sum64(ms1);
    ms2 = red_sum64(ms2); ms3 = red_sum64(ms3);   // valid in lane 63

    double s2 = 0.0;                              // sum log2(max), lane 63
    float4 dcur = make_float4(0,0,0,0), dnext = dcur;
    if (lane == 63) dcur = *(const float4*)(decoded + r0);

    for (int t = 0; t < TSTEPS; ++t) {
        // off-critical-path: emissions for this step + prefetch next
        const float ex0 = __expf(dcur.x), ex1 = __expf(dcur.y);
        const float ex2 = __expf(dcur.z), ex3 = __expf(dcur.w);
        if (lane == 63 && t + 1 < TSTEPS)
            dnext = *(const float4*)(decoded + (size_t)(t + 1) * NTAGS + r0);

        const float sg = ((t >> 1) & 1) ? -1.0f : 1.0f;

        float q[16];                              // raw stored-form values
        if (t == 0) {
            #pragma unroll
            for (int j = 0; j < 16; ++j)
                q[j] = (c0 + j == START_I) ? 2.0f : 1.0f;   // p+1, sg=+1
        } else {
            const float* src = ring + (size_t)(t & 1) * NTAGS + c0;
            f32x4 A, B, C, D;
            if (sg > 0.0f) {
                for (;;) {
                    llc_load64B(src, A, B, C, D);
                    if (hmin16(A, B, C, D) >= 1.0f) break;
                }
            } else {
                for (;;) {
                    llc_load64B(src, A, B, C, D);
                    if (hmax16(A, B, C, D) <= -1.0f) break;
                }
            }
            q[0]=A.x; q[1]=A.y; q[2]=A.z;  q[3]=A.w;
            q[4]=B.x; q[5]=B.y; q[6]=B.z;  q[7]=B.w;
            q[8]=C.x; q[9]=C.y; q[10]=C.z; q[11]=C.w;
            q[12]=D.x; q[13]=D.y; q[14]=D.z; q[15]=D.w;
        }

        // per-lane extreme of raw q -> global max of (p+1)
        float ext = q[0];
        if (sg > 0.0f) {
            #pragma unroll
            for (int j = 1; j < 16; ++j) ext = fmaxf(ext, q[j]);
        } else {
            #pragma unroll
            for (int j = 1; j < 16; ++j) ext = fminf(ext, q[j]);
        }
        float mp1 = red_max64(sg * ext);          // lane 63: max(p)+1

        // 4-row dot products on raw q (sign/offset folded via msum)
        float a0=0.f, a1=0.f, a2=0.f, a3=0.f;
        #pragma unroll
        for (int j = 0; j < 16; ++j) {
            a0 = fmaf(M0[j], q[j], a0);
            a1 = fmaf(M1[j], q[j], a1);
            a2 = fmaf(M2[j], q[j], a2);
            a3 = fmaf(M3[j], q[j], a3);
        }
        a0 = red_sum64(a0); a1 = red_sum64(a1);
        a2 = red_sum64(a2); a3 = red_sum64(a3);

        if (lane == 63) {
            const float m  = mp1 - 1.0f;
            const float sc = __builtin_amdgcn_rcpf(m);
            // s_r = sg*a_r - msum_r = sum_c M[r,c] * p[c]
            const float o0 = fmaxf(ex0 * fmaf(sg, a0, -ms0) * sc, 0.0f);
            const float o1 = fmaxf(ex1 * fmaf(sg, a1, -ms1) * sc, 0.0f);
            const float o2 = fmaxf(ex2 * fmaf(sg, a2, -ms2) * sc, 0.0f);
            const float o3 = fmaxf(ex3 * fmaf(sg, a3, -ms3) * sc, 0.0f);
            s2 += (double)__log2f(m);
            const int   tn  = t + 1;
            const float sgn = ((tn >> 1) & 1) ? -1.0f : 1.0f;
            float* dst = ring + (size_t)(tn & 1) * NTAGS + 4 * wg;
            __hip_atomic_store((unsigned long long*)dst,
                               pk2(fmaf(sgn, o0, sgn), fmaf(sgn, o1, sgn)),
                               __ATOMIC_RELAXED, __HIP_MEMORY_SCOPE_AGENT);
            __hip_atomic_store((unsigned long long*)(dst + 2),
                               pk2(fmaf(sgn, o2, sgn), fmaf(sgn, o3, sgn)),
                               __ATOMIC_RELAXED, __HIP_MEMORY_SCOPE_AGENT);
        }
        dcur = dnext;
    }

    // ---- epilogue (wg 0): fold in trans[STOP,:] ----
    if (wg == 0) {
        // p_T: slot (16384&1)=0, sign ((16384>>1)&1)=0 -> positive phase
        const float* src = ring + c0;
        f32x4 A, B, C, D;
        for (;;) {
            llc_load64B(src, A, B, C, D);
            if (hmin16(A, B, C, D) >= 1.0f) break;
        }
        float q[16] = {A.x,A.y,A.z,A.w, B.x,B.y,B.z,B.w,
                       C.x,C.y,C.z,C.w, D.x,D.y,D.z,D.w};
        float term = 0.0f;
        #pragma unroll
        for (int j = 0; j < 16; ++j)
            term = fmaf(__expf(trans[(size_t)STOP_I * NTAGS + c0 + j]),
                        q[j] - 1.0f, term);
        term = red_sum64(term);
        if (lane == 63)
            out[0] = (float)(0.6931471805599453 * (s2 + log2((double)term)));
    }
}

extern "C" void kernel_launch(void* const* d_in, const int* in_sizes, int n_in,
                              void* d_out, int out_size, void* d_ws, size_t ws_size,
                              hipStream_t stream) {
    const float* decoded = (const float*)d_in[0];   // [16384, 1024] f32
    const float* trans   = (const float*)d_in[1];   // [1024, 1024]  f32
    float* out  = (float*)d_out;
    float* ring = (float*)d_ws;                     // 2 * 1024 f32 = 8 KB

    hipMemsetAsync(ring, 0xAA, 2 * NTAGS * sizeof(float), stream);

    hipLaunchKernelGGL(crf_forward_kernel, dim3(NWG), dim3(TPB), 0, stream,
                       decoded, trans, out, ring);
}